// Round 5
// baseline (152.055 us; speedup 1.0000x reference)
//
#include <hip/hip_runtime.h>
#include <math.h>

#define Bn 256
#define Nn 1024
#define Dn 128
#define Hn 8
#define HDn 16
#define NEG_INF -1.0e15f

#define AS(n) __attribute__((address_space(n)))
#define WAITV(n) asm volatile("s_waitcnt vmcnt(" #n ")" ::: "memory")

__device__ __forceinline__ void gl_lds16(const float* g, float* l) {
    __builtin_amdgcn_global_load_lds(
        (AS(1) void*)(unsigned long long)g,
        (AS(3) void*)l, 16, 0, 0);
}

// ---------------- K0: Q = h_c @ Wq.T + bq ----------------
__global__ __launch_bounds__(128) void k_q(
    const float* __restrict__ h_g, const float* __restrict__ first,
    const float* __restrict__ last, const float* __restrict__ context,
    const float* __restrict__ Wq, const float* __restrict__ bq,
    float* __restrict__ Qout)
{
    __shared__ __align__(16) float hc[3 * Dn + 2];
    const int b = blockIdx.x;
    const int t = threadIdx.x;
    hc[t]          = h_g[b * Dn + t];
    hc[Dn + t]     = first[b * Dn + t];
    hc[2 * Dn + t] = last[b * Dn + t];
    if (t < 2) hc[3 * Dn + t] = context[b * 2 + t];
    __syncthreads();

    const float2* w2 = (const float2*)(Wq + (size_t)t * (3 * Dn + 2));
    const float2* h2 = (const float2*)hc;
    float acc = bq[t];
#pragma unroll 8
    for (int k = 0; k < (3 * Dn + 2) / 2; ++k) {
        float2 w = w2[k], h = h2[k];
        acc = fmaf(w.x, h.x, fmaf(w.y, h.y, acc));
    }
    Qout[b * Dn + t] = acc;
}

// ---------------- K1: attention via global_load_lds async pipeline ----------------
// Block=(b,h), 128 threads. 8 chunks of 128 keys; K/V chunk (8KB each) staged
// by async DMA into triple-buffered LDS; counted vmcnt keeps the next chunk's
// loads in flight across the barrier (never drain to 0 mid-loop).
__global__ __launch_bounds__(128) void k_attn(
    const float* __restrict__ Q, const float* __restrict__ K,
    const float* __restrict__ V, const int* __restrict__ mask,
    float* __restrict__ Uout)
{
    __shared__ __align__(16) float sK[3 * 2048];   // 3 bufs x 128 keys x 16 f
    __shared__ __align__(16) float sV[3 * 2048];
    __shared__ float sTot;

    const int bh = blockIdx.x;
    const int b = bh >> 3, h = bh & 7;
    const int tid = threadIdx.x;

    // --- registers loaded up front; drained before staging so vmcnt counts clean
    const int* __restrict__ mrow = mask + (size_t)b * Nn;
    int mk[8];
#pragma unroll
    for (int c = 0; c < 8; ++c) mk[c] = mrow[c * 128 + tid];
    float4 q4[4];
#pragma unroll
    for (int j = 0; j < 4; ++j)
        q4[j] = ((const float4*)(Q + (size_t)b * Dn + h * HDn))[j];
    WAITV(0);
    __builtin_amdgcn_sched_barrier(0);

    const float4* __restrict__ Kg = (const float4*)(K + (size_t)bh * Nn * HDn);
    const float4* __restrict__ Vg = (const float4*)(V + (size_t)bh * Nn * HDn);

    // stage chunk c into buffer buf (8 calls: 4 K rounds + 4 V rounds)
#define STAGE(c, buf)                                                        \
    {                                                                        \
        const int g0 = (c) * 512 + tid;                                      \
        _Pragma("unroll")                                                    \
        for (int rr = 0; rr < 4; ++rr)                                       \
            gl_lds16((const float*)(Kg + g0 + rr * 128),                     \
                     sK + (buf) * 2048 + (rr * 128 + tid) * 4);              \
        _Pragma("unroll")                                                    \
        for (int rr = 0; rr < 4; ++rr)                                       \
            gl_lds16((const float*)(Vg + g0 + rr * 128),                     \
                     sV + (buf) * 2048 + (rr * 128 + tid) * 4);              \
    }

    STAGE(0, 0);
    STAGE(1, 1);

    const int rot = (tid >> 1) & 3;
    float4 u0 = {0,0,0,0}, u1 = {0,0,0,0}, u2 = {0,0,0,0}, u3 = {0,0,0,0};
    float sum = 0.f;

#pragma unroll
    for (int c = 0; c < 8; ++c) {
        if (c < 7) { WAITV(8); } else { WAITV(0); }   // chunk c landed (own calls)
        __builtin_amdgcn_sched_barrier(0);
        __builtin_amdgcn_s_barrier();                  // all waves' chunk c landed
        __builtin_amdgcn_sched_barrier(0);
        if (c < 6) {
            if ((c & 1) == 0) { STAGE(c + 2, (c + 2) % 3); }
            else              { STAGE(c + 2, (c + 2) % 3); }
        }
        // compute chunk c from LDS buffer c%3 (rotated granule order: bank-free)
        const float4* kb4 = (const float4*)(sK + (c % 3) * 2048);
        const float4* vb4 = (const float4*)(sV + (c % 3) * 2048);
        float s = 0.f;
        float4 kgr[4];
#pragma unroll
        for (int j = 0; j < 4; ++j) {
            const int jj = (j + rot) & 3;
            kgr[jj] = kb4[tid * 4 + jj];
        }
#pragma unroll
        for (int jj = 0; jj < 4; ++jj) {
            s = fmaf(q4[jj].x, kgr[jj].x, s);
            s = fmaf(q4[jj].y, kgr[jj].y, s);
            s = fmaf(q4[jj].z, kgr[jj].z, s);
            s = fmaf(q4[jj].w, kgr[jj].w, s);
        }
        const float e = mk[c] ? __expf(s * 0.25f) : 0.f;   // /sqrt(16)
        sum += e;
#pragma unroll
        for (int j = 0; j < 4; ++j) {
            const int jj = (j + rot) & 3;
            const float4 vv = vb4[tid * 4 + jj];
            if (jj == 0) { u0.x=fmaf(e,vv.x,u0.x); u0.y=fmaf(e,vv.y,u0.y); u0.z=fmaf(e,vv.z,u0.z); u0.w=fmaf(e,vv.w,u0.w); }
            else if (jj == 1) { u1.x=fmaf(e,vv.x,u1.x); u1.y=fmaf(e,vv.y,u1.y); u1.z=fmaf(e,vv.z,u1.z); u1.w=fmaf(e,vv.w,u1.w); }
            else if (jj == 2) { u2.x=fmaf(e,vv.x,u2.x); u2.y=fmaf(e,vv.y,u2.y); u2.z=fmaf(e,vv.z,u2.z); u2.w=fmaf(e,vv.w,u2.w); }
            else { u3.x=fmaf(e,vv.x,u3.x); u3.y=fmaf(e,vv.y,u3.y); u3.z=fmaf(e,vv.z,u3.z); u3.w=fmaf(e,vv.w,u3.w); }
        }
    }
#undef STAGE

    // ---- block reduction of per-thread partials (reuse sK as scratch) ----
    __builtin_amdgcn_s_barrier();          // everyone done reading LDS bufs
    float* P = sK;
    {
        float* p = P + tid * 17;
        p[0]=u0.x; p[1]=u0.y; p[2]=u0.z; p[3]=u0.w;
        p[4]=u1.x; p[5]=u1.y; p[6]=u1.z; p[7]=u1.w;
        p[8]=u2.x; p[9]=u2.y; p[10]=u2.z; p[11]=u2.w;
        p[12]=u3.x; p[13]=u3.y; p[14]=u3.z; p[15]=u3.w;
        p[16]=sum;
    }
    __builtin_amdgcn_s_barrier();
    float acc = 0.f;
    if (tid < 17) {
#pragma unroll 16
        for (int j = 0; j < 128; ++j) acc += P[j * 17 + tid];
        if (tid == 16) sTot = acc;
    }
    __builtin_amdgcn_s_barrier();
    if (tid < 16) {
        Uout[(size_t)b * Dn + h * HDn + tid] = acc / sTot;
    }
}

// ---------------- K2: u2 = u@Wo.T + bo; pointer logits; softmax; argmax ----------------
__global__ __launch_bounds__(1024) void k_ptr(
    const float* __restrict__ U, const float* __restrict__ Wo,
    const float* __restrict__ bo, const float* __restrict__ K_lg,
    const int* __restrict__ mask, float* __restrict__ out)
{
    __shared__ __align__(16) float sU[Dn];
    __shared__ __align__(16) float sU2[Dn];
    __shared__ __align__(16) float sL[Nn];
    __shared__ float sRv[16];
    __shared__ int   sRi[16];
    __shared__ float sRs[16];

    const int b = blockIdx.x;
    const int tid = threadIdx.x;
    const int lane = tid & 63, wave = tid >> 6;

    if (tid < Dn) sU[tid] = U[b * Dn + tid];
    __syncthreads();
    // u2: 8 threads per output dim (1024 thr / 128 dims)
    {
        const int d = tid >> 3, e8 = tid & 7;
        const float4* wrow = (const float4*)(Wo + (size_t)d * Dn + e8 * 16);
        const float4* su4 = (const float4*)(sU + e8 * 16);
        float acc = 0.f;
#pragma unroll
        for (int k = 0; k < 4; ++k) {
            const float4 w = wrow[k], u = su4[k];
            acc = fmaf(w.x, u.x, fmaf(w.y, u.y, fmaf(w.z, u.z, fmaf(w.w, u.w, acc))));
        }
        acc += __shfl_xor(acc, 1, 64);
        acc += __shfl_xor(acc, 2, 64);
        acc += __shfl_xor(acc, 4, 64);
        if (e8 == 0) sU2[d] = acc + bo[d];
    }
    __syncthreads();

    // logits: 32 groups of 32 lanes; 4-deep batched loads
    const float4* __restrict__ Kl = (const float4*)(K_lg + (size_t)b * Nn * Dn);
    const int* __restrict__ mrow = mask + (size_t)b * Nn;
    const int grp = tid >> 5, l32 = tid & 31;
    const float4 u2f = ((const float4*)sU2)[l32];
    const float sc = 0.08838834764831845f;   // 1/sqrt(128)
#pragma unroll
    for (int it0 = 0; it0 < 32; it0 += 4) {
        float4 kl[4];
#pragma unroll
        for (int j = 0; j < 4; ++j)
            kl[j] = Kl[(size_t)(grp + 32 * (it0 + j)) * 32 + l32];
        __builtin_amdgcn_sched_barrier(0);
#pragma unroll
        for (int j = 0; j < 4; ++j) {
            float p = kl[j].x * u2f.x + kl[j].y * u2f.y + kl[j].z * u2f.z + kl[j].w * u2f.w;
#pragma unroll
            for (int o = 16; o >= 1; o >>= 1) p += __shfl_xor(p, o, 64);
            if (l32 == 0) {
                const int n = grp + 32 * (it0 + j);
                sL[n] = (mrow[n] == 0) ? NEG_INF : 10.0f * tanhf(p * sc);
            }
        }
    }
    __syncthreads();

    // block argmax (first-occurrence tie-break) — one key per thread
    float bv = sL[tid]; int bi = tid;
#pragma unroll
    for (int o = 32; o >= 1; o >>= 1) {
        const float ov = __shfl_xor(bv, o, 64);
        const int oi = __shfl_xor(bi, o, 64);
        if (ov > bv || (ov == bv && oi < bi)) { bv = ov; bi = oi; }
    }
    if (lane == 0) { sRv[wave] = bv; sRi[wave] = bi; }
    __syncthreads();
    bv = sRv[0]; bi = sRi[0];
#pragma unroll
    for (int w = 1; w < 16; ++w) {
        const float ov = sRv[w]; const int oi = sRi[w];
        if (ov > bv || (ov == bv && oi < bi)) { bv = ov; bi = oi; }
    }

    // sum of exp(l - max); prob at argmax = 1/sum
    float lsum = __expf(sL[tid] - bv);
#pragma unroll
    for (int o = 32; o >= 1; o >>= 1) lsum += __shfl_xor(lsum, o, 64);
    if (lane == 0) sRs[wave] = lsum;
    __syncthreads();
    if (tid == 0) {
        float tot = 0.f;
#pragma unroll
        for (int w = 0; w < 16; ++w) tot += sRs[w];
        out[b] = (float)bi;            // vertexes (as float32 values)
        out[Bn + b] = 1.0f / tot;      // probs
    }
}

extern "C" void kernel_launch(void* const* d_in, const int* in_sizes, int n_in,
                              void* d_out, int out_size, void* d_ws, size_t ws_size,
                              hipStream_t stream) {
    // inputs: x, h_g, first, last, context, K, V, K_lg, Wq, bq, Wo, bo, mask, t
    const float* h_g     = (const float*)d_in[1];
    const float* first   = (const float*)d_in[2];
    const float* last    = (const float*)d_in[3];
    const float* context = (const float*)d_in[4];
    const float* K       = (const float*)d_in[5];
    const float* V       = (const float*)d_in[6];
    const float* K_lg    = (const float*)d_in[7];
    const float* Wq      = (const float*)d_in[8];
    const float* bq      = (const float*)d_in[9];
    const float* Wo      = (const float*)d_in[10];
    const float* bo      = (const float*)d_in[11];
    const int*   mask    = (const int*)d_in[12];
    float* out = (float*)d_out;

    float* Qws = (float*)d_ws;             // B*D floats
    float* Uws = Qws + Bn * Dn;            // B*D floats

    k_q   <<<Bn,      128, 0, stream>>>(h_g, first, last, context, Wq, bq, Qws);
    k_attn<<<Bn * Hn, 128, 0, stream>>>(Qws, K, V, mask, Uws);
    k_ptr <<<Bn,     1024, 0, stream>>>(Uws, Wo, bo, K_lg, mask, out);
}

// Round 6
// 113.556 us; speedup vs baseline: 1.3390x; 1.3390x over previous
//
#include <hip/hip_runtime.h>
#include <math.h>

#define Bn 256
#define Nn 1024
#define Dn 128
#define Hn 8
#define HDn 16
#define NEG_INF -1.0e15f

#define AS(n) __attribute__((address_space(n)))
#define WAITV(n) asm volatile("s_waitcnt vmcnt(" #n ")" ::: "memory")

__device__ __forceinline__ void gl_lds16(const float* g, float* l) {
    __builtin_amdgcn_global_load_lds(
        (AS(1) void*)(unsigned long long)g,
        (AS(3) void*)l, 16, 0, 0);
}

// ---------------- K0: Q = h_c @ Wq.T + bq ----------------
__global__ __launch_bounds__(128) void k_q(
    const float* __restrict__ h_g, const float* __restrict__ first,
    const float* __restrict__ last, const float* __restrict__ context,
    const float* __restrict__ Wq, const float* __restrict__ bq,
    float* __restrict__ Qout)
{
    __shared__ __align__(16) float hc[3 * Dn + 2];
    const int b = blockIdx.x;
    const int t = threadIdx.x;
    hc[t]          = h_g[b * Dn + t];
    hc[Dn + t]     = first[b * Dn + t];
    hc[2 * Dn + t] = last[b * Dn + t];
    if (t < 2) hc[3 * Dn + t] = context[b * 2 + t];
    __syncthreads();

    const float2* w2 = (const float2*)(Wq + (size_t)t * (3 * Dn + 2));
    const float2* h2 = (const float2*)hc;
    float acc = bq[t];
#pragma unroll 8
    for (int k = 0; k < (3 * Dn + 2) / 2; ++k) {
        float2 w = w2[k], h = h2[k];
        acc = fmaf(w.x, h.x, fmaf(w.y, h.y, acc));
    }
    Qout[b * Dn + t] = acc;
}

// ---------------- K1: async-DMA attention, clean counted-vmcnt pipeline ----------------
// Block=(b,h), 256 threads (4 waves). 8 chunks x 128 keys; K/V chunk (8KB each)
// staged via global_load_lds into double-buffered LDS. Counted WAITV(4) keeps
// the next chunk's DMA in flight across the barrier. 4 lanes per key: LDS
// reads are lane-linear (byte addr = lane*16) -> conflict-free, no swizzle,
// no runtime-indexed register arrays (R5's scratch bug).
__global__ __launch_bounds__(256) void k_attn(
    const float* __restrict__ Q, const float* __restrict__ K,
    const float* __restrict__ V, const int* __restrict__ mask,
    float* __restrict__ Uout)
{
    __shared__ __align__(16) float sK[2 * 2048];   // 2 bufs x 128 keys x 16 f
    __shared__ __align__(16) float sV[2 * 2048];
    __shared__ __align__(16) float sP[16 * 4];     // per-wave granule partials
    __shared__ float sS[4];

    const int bh = blockIdx.x;
    const int b = bh >> 3, h = bh & 7;
    const int tid = threadIdx.x;
    const int lane = tid & 63, wave = tid >> 6;
    const int g = tid & 3;          // granule (4 floats of the 16-dim head)
    const int kq = tid >> 2;        // key-quad 0..63

    // up-front register loads; drained before staging so vmcnt counts only DMA
    const int* __restrict__ mrow = mask + (size_t)b * Nn;
    int mk[16];
#pragma unroll
    for (int c = 0; c < 8; ++c) {
        mk[c * 2]     = mrow[c * 128 + kq];
        mk[c * 2 + 1] = mrow[c * 128 + 64 + kq];
    }
    const float4 qg = ((const float4*)(Q + (size_t)b * Dn + h * HDn))[g];
    WAITV(0);
    __builtin_amdgcn_sched_barrier(0);

    const float4* __restrict__ Kg = (const float4*)(K + (size_t)bh * Nn * HDn);
    const float4* __restrict__ Vg = (const float4*)(V + (size_t)bh * Nn * HDn);

    // stage chunk c (128 keys = 512 float4 granules of K and of V) into buf
#define STAGE(c, buf) {                                                       \
    gl_lds16((const float*)(Kg + (c) * 512 + tid),       sK + (buf) * 2048 + tid * 4);        \
    gl_lds16((const float*)(Kg + (c) * 512 + 256 + tid), sK + (buf) * 2048 + 1024 + tid * 4); \
    gl_lds16((const float*)(Vg + (c) * 512 + tid),       sV + (buf) * 2048 + tid * 4);        \
    gl_lds16((const float*)(Vg + (c) * 512 + 256 + tid), sV + (buf) * 2048 + 1024 + tid * 4); \
}

    STAGE(0, 0);
    STAGE(1, 1);

    float4 u = {0.f, 0.f, 0.f, 0.f};
    float sum = 0.f;

#pragma unroll
    for (int c = 0; c < 8; ++c) {
        if (c < 7) { WAITV(4); } else { WAITV(0); }   // own chunk-c DMAs landed
        __builtin_amdgcn_sched_barrier(0);
        __builtin_amdgcn_s_barrier();                 // all waves' chunk c landed
        const float* kb = sK + (c & 1) * 2048;
        const float* vb = sV + (c & 1) * 2048;
#pragma unroll
        for (int kk = 0; kk < 2; ++kk) {
            const int key = kq + 64 * kk;
            const float4 kf = *(const float4*)(kb + key * 16 + g * 4);  // lane-linear
            const float4 vf = *(const float4*)(vb + key * 16 + g * 4);
            float p = qg.x * kf.x + qg.y * kf.y + qg.z * kf.z + qg.w * kf.w;
            p += __shfl_xor(p, 1, 64);
            p += __shfl_xor(p, 2, 64);               // full 16-dot in all 4 lanes
            const float e = mk[c * 2 + kk] ? __expf(p * 0.25f) : 0.f;  // /sqrt(16)
            sum += e;
            u.x = fmaf(e, vf.x, u.x);
            u.y = fmaf(e, vf.y, u.y);
            u.z = fmaf(e, vf.z, u.z);
            u.w = fmaf(e, vf.w, u.w);
        }
        __builtin_amdgcn_s_barrier();                 // buf (c&1) free for re-stage
        if (c < 6) STAGE(c + 2, c & 1);
    }
#undef STAGE

    // reduce across the 16 key-quads of each wave (lane bits 2..5)
#pragma unroll
    for (int o = 4; o <= 32; o <<= 1) {
        u.x += __shfl_xor(u.x, o, 64);
        u.y += __shfl_xor(u.y, o, 64);
        u.z += __shfl_xor(u.z, o, 64);
        u.w += __shfl_xor(u.w, o, 64);
        sum += __shfl_xor(sum, o, 64);
    }
    if (lane < 4) ((float4*)sP)[wave * 4 + lane] = u;
    if (lane == 0) sS[wave] = sum;
    __syncthreads();
    if (tid < 4) {
        const float4 t0 = ((const float4*)sP)[0 * 4 + tid];
        const float4 t1 = ((const float4*)sP)[1 * 4 + tid];
        const float4 t2 = ((const float4*)sP)[2 * 4 + tid];
        const float4 t3 = ((const float4*)sP)[3 * 4 + tid];
        const float inv = 1.0f / (sS[0] + sS[1] + sS[2] + sS[3]);
        float4 r;
        r.x = (t0.x + t1.x + t2.x + t3.x) * inv;
        r.y = (t0.y + t1.y + t2.y + t3.y) * inv;
        r.z = (t0.z + t1.z + t2.z + t3.z) * inv;
        r.w = (t0.w + t1.w + t2.w + t3.w) * inv;
        ((float4*)(Uout + (size_t)b * Dn + h * HDn))[tid] = r;
    }
}

// ---------------- K2: u2 = u@Wo.T + bo; pointer logits; softmax; argmax ----------------
__global__ __launch_bounds__(1024) void k_ptr(
    const float* __restrict__ U, const float* __restrict__ Wo,
    const float* __restrict__ bo, const float* __restrict__ K_lg,
    const int* __restrict__ mask, float* __restrict__ out)
{
    __shared__ __align__(16) float sU[Dn];
    __shared__ __align__(16) float sU2[Dn];
    __shared__ __align__(16) float sL[Nn];
    __shared__ float sRv[16];
    __shared__ int   sRi[16];
    __shared__ float sRs[16];

    const int b = blockIdx.x;
    const int tid = threadIdx.x;
    const int lane = tid & 63, wave = tid >> 6;

    if (tid < Dn) sU[tid] = U[b * Dn + tid];
    __syncthreads();
    // u2: 8 threads per output dim (1024 thr / 128 dims)
    {
        const int d = tid >> 3, e8 = tid & 7;
        const float4* wrow = (const float4*)(Wo + (size_t)d * Dn + e8 * 16);
        const float4* su4 = (const float4*)(sU + e8 * 16);
        float acc = 0.f;
#pragma unroll
        for (int k = 0; k < 4; ++k) {
            const float4 w = wrow[k], u = su4[k];
            acc = fmaf(w.x, u.x, fmaf(w.y, u.y, fmaf(w.z, u.z, fmaf(w.w, u.w, acc))));
        }
        acc += __shfl_xor(acc, 1, 64);
        acc += __shfl_xor(acc, 2, 64);
        acc += __shfl_xor(acc, 4, 64);
        if (e8 == 0) sU2[d] = acc + bo[d];
    }
    __syncthreads();

    // logits: 32 groups of 32 lanes; 4-deep batched loads
    const float4* __restrict__ Kl = (const float4*)(K_lg + (size_t)b * Nn * Dn);
    const int* __restrict__ mrow = mask + (size_t)b * Nn;
    const int grp = tid >> 5, l32 = tid & 31;
    const float4 u2f = ((const float4*)sU2)[l32];
    const float sc = 0.08838834764831845f;   // 1/sqrt(128)
#pragma unroll
    for (int it0 = 0; it0 < 32; it0 += 4) {
        float4 kl[4];
#pragma unroll
        for (int j = 0; j < 4; ++j)
            kl[j] = Kl[(size_t)(grp + 32 * (it0 + j)) * 32 + l32];
        __builtin_amdgcn_sched_barrier(0);
#pragma unroll
        for (int j = 0; j < 4; ++j) {
            float p = kl[j].x * u2f.x + kl[j].y * u2f.y + kl[j].z * u2f.z + kl[j].w * u2f.w;
#pragma unroll
            for (int o = 16; o >= 1; o >>= 1) p += __shfl_xor(p, o, 64);
            if (l32 == 0) {
                const int n = grp + 32 * (it0 + j);
                sL[n] = (mrow[n] == 0) ? NEG_INF : 10.0f * tanhf(p * sc);
            }
        }
    }
    __syncthreads();

    // block argmax (first-occurrence tie-break) — one key per thread
    float bv = sL[tid]; int bi = tid;
#pragma unroll
    for (int o = 32; o >= 1; o >>= 1) {
        const float ov = __shfl_xor(bv, o, 64);
        const int oi = __shfl_xor(bi, o, 64);
        if (ov > bv || (ov == bv && oi < bi)) { bv = ov; bi = oi; }
    }
    if (lane == 0) { sRv[wave] = bv; sRi[wave] = bi; }
    __syncthreads();
    bv = sRv[0]; bi = sRi[0];
#pragma unroll
    for (int w = 1; w < 16; ++w) {
        const float ov = sRv[w]; const int oi = sRi[w];
        if (ov > bv || (ov == bv && oi < bi)) { bv = ov; bi = oi; }
    }

    // sum of exp(l - max); prob at argmax = 1/sum
    float lsum = __expf(sL[tid] - bv);
#pragma unroll
    for (int o = 32; o >= 1; o >>= 1) lsum += __shfl_xor(lsum, o, 64);
    if (lane == 0) sRs[wave] = lsum;
    __syncthreads();
    if (tid == 0) {
        float tot = 0.f;
#pragma unroll
        for (int w = 0; w < 16; ++w) tot += sRs[w];
        out[b] = (float)bi;            // vertexes (as float32 values)
        out[Bn + b] = 1.0f / tot;      // probs
    }
}

extern "C" void kernel_launch(void* const* d_in, const int* in_sizes, int n_in,
                              void* d_out, int out_size, void* d_ws, size_t ws_size,
                              hipStream_t stream) {
    // inputs: x, h_g, first, last, context, K, V, K_lg, Wq, bq, Wo, bo, mask, t
    const float* h_g     = (const float*)d_in[1];
    const float* first   = (const float*)d_in[2];
    const float* last    = (const float*)d_in[3];
    const float* context = (const float*)d_in[4];
    const float* K       = (const float*)d_in[5];
    const float* V       = (const float*)d_in[6];
    const float* K_lg    = (const float*)d_in[7];
    const float* Wq      = (const float*)d_in[8];
    const float* bq      = (const float*)d_in[9];
    const float* Wo      = (const float*)d_in[10];
    const float* bo      = (const float*)d_in[11];
    const int*   mask    = (const int*)d_in[12];
    float* out = (float*)d_out;

    float* Qws = (float*)d_ws;             // B*D floats
    float* Uws = Qws + Bn * Dn;            // B*D floats

    k_q   <<<Bn,      128, 0, stream>>>(h_g, first, last, context, Wq, bq, Qws);
    k_attn<<<Bn * Hn, 256, 0, stream>>>(Qws, K, V, mask, Uws);
    k_ptr <<<Bn,     1024, 0, stream>>>(Uws, Wo, bo, K_lg, mask, out);
}

// Round 8
// 106.570 us; speedup vs baseline: 1.4268x; 1.0656x over previous
//
#include <hip/hip_runtime.h>
#include <math.h>

#define Bn 256
#define Nn 1024
#define Dn 128
#define Hn 8
#define HDn 16
#define NEG_INF -1.0e15f

typedef float v4f __attribute__((ext_vector_type(4)));

// ---------------- K0: Q = h_c @ Wq.T + bq ----------------
__global__ __launch_bounds__(128) void k_q(
    const float* __restrict__ h_g, const float* __restrict__ first,
    const float* __restrict__ last, const float* __restrict__ context,
    const float* __restrict__ Wq, const float* __restrict__ bq,
    float* __restrict__ Qout)
{
    __shared__ __align__(16) float hc[3 * Dn + 2];
    const int b = blockIdx.x;
    const int t = threadIdx.x;
    hc[t]          = h_g[b * Dn + t];
    hc[Dn + t]     = first[b * Dn + t];
    hc[2 * Dn + t] = last[b * Dn + t];
    if (t < 2) hc[3 * Dn + t] = context[b * 2 + t];
    __syncthreads();

    const float2* w2 = (const float2*)(Wq + (size_t)t * (3 * Dn + 2));
    const float2* h2 = (const float2*)hc;
    float acc = bq[t];
#pragma unroll 8
    for (int k = 0; k < (3 * Dn + 2) / 2; ++k) {
        float2 w = w2[k], h = h2[k];
        acc = fmaf(w.x, h.x, fmaf(w.y, h.y, acc));
    }
    Qout[b * Dn + t] = acc;
}

// ---------------- K1: one block per batch element; long linear streams ----------------
// 256 blocks x 1024 threads (16 waves). Block b loops over its 8 heads; per
// pass the block reads a contiguous 16KB slab of K then V (float4 index
// = p*1024 + tid). 4 lanes per key; single-pass softmax (no max-subtraction,
// scores ~N(0,1)); one barrier pair at the end.
__global__ __launch_bounds__(1024) void k_attn(
    const float* __restrict__ Q, const float* __restrict__ K,
    const float* __restrict__ V, const int* __restrict__ mask,
    float* __restrict__ Uout)
{
    __shared__ __align__(16) float sPart[16][Hn][20];  // [wave][head][16 u + sum]
    __shared__ __align__(16) float sTot[Hn][20];

    const int b = blockIdx.x;
    const int tid = threadIdx.x;
    const int lane = tid & 63, wave = tid >> 6;
    const int g = tid & 3;            // granule of the 16-dim head
    const int kq = tid >> 2;          // key-quad 0..255

    // mask for this thread's 4 keys (shared across all 8 heads)
    const int* __restrict__ mrow = mask + (size_t)b * Nn;
    int mk[4];
#pragma unroll
    for (int p = 0; p < 4; ++p) mk[p] = mrow[p * 256 + kq];

    const float4* __restrict__ Qrow = (const float4*)(Q + (size_t)b * Dn);
    const float4* __restrict__ Kb = (const float4*)(K + (size_t)b * Hn * Nn * HDn);
    const float4* __restrict__ Vb = (const float4*)(V + (size_t)b * Hn * Nn * HDn);

#pragma unroll
    for (int s = 0; s < Hn; ++s) {
        const float4 qg = Qrow[s * 4 + g];
        const float4* __restrict__ Kh = Kb + (size_t)s * 4096;
        const float4* __restrict__ Vh = Vb + (size_t)s * 4096;

        float4 kf[4], vf[4];
#pragma unroll
        for (int p = 0; p < 4; ++p) kf[p] = Kh[p * 1024 + tid];   // 16KB linear slab
#pragma unroll
        for (int p = 0; p < 4; ++p) vf[p] = Vh[p * 1024 + tid];
        __builtin_amdgcn_sched_barrier(0);    // keep the 8 loads issued up front

        float4 u = {0.f, 0.f, 0.f, 0.f};
        float sum = 0.f;
#pragma unroll
        for (int p = 0; p < 4; ++p) {
            float sc = qg.x * kf[p].x + qg.y * kf[p].y + qg.z * kf[p].z + qg.w * kf[p].w;
            sc += __shfl_xor(sc, 1, 64);
            sc += __shfl_xor(sc, 2, 64);      // full 16-dot in all 4 lanes of the quad
            const float e = mk[p] ? __expf(sc * 0.25f) : 0.f;   // /sqrt(16)
            sum += e;
            u.x = fmaf(e, vf[p].x, u.x);
            u.y = fmaf(e, vf[p].y, u.y);
            u.z = fmaf(e, vf[p].z, u.z);
            u.w = fmaf(e, vf[p].w, u.w);
        }
        // reduce across the 16 quads of this wave (lane bits 2..5)
#pragma unroll
        for (int o = 4; o <= 32; o <<= 1) {
            u.x += __shfl_xor(u.x, o, 64);
            u.y += __shfl_xor(u.y, o, 64);
            u.z += __shfl_xor(u.z, o, 64);
            u.w += __shfl_xor(u.w, o, 64);
            sum += __shfl_xor(sum, o, 64);
        }
        if (lane < 4) *(float4*)(&sPart[wave][s][lane * 4]) = u;
        if (lane == 0) sPart[wave][s][16] = sum;
    }
    __syncthreads();

    // totals: 8 heads x 17 values, each summed over 16 waves
    if (tid < Hn * 17) {
        const int s = tid / 17, j = tid % 17;
        float a = 0.f;
#pragma unroll
        for (int w = 0; w < 16; ++w) a += sPart[w][s][j];
        sTot[s][j] = a;
    }
    __syncthreads();
    if (tid < Dn) {
        const int s = tid >> 4, j = tid & 15;
        Uout[(size_t)b * Dn + tid] = sTot[s][j] / sTot[s][16];
    }
}

// ---------------- K2: u2 = u@Wo.T + bo; pointer logits; softmax; argmax ----------------
__global__ __launch_bounds__(1024) void k_ptr(
    const float* __restrict__ U, const float* __restrict__ Wo,
    const float* __restrict__ bo, const float* __restrict__ K_lg,
    const int* __restrict__ mask, float* __restrict__ out)
{
    __shared__ __align__(16) float sU[Dn];
    __shared__ __align__(16) float sU2[Dn];
    __shared__ __align__(16) float sL[Nn];
    __shared__ float sRv[16];
    __shared__ int   sRi[16];
    __shared__ float sRs[16];

    const int b = blockIdx.x;
    const int tid = threadIdx.x;
    const int lane = tid & 63, wave = tid >> 6;

    if (tid < Dn) sU[tid] = U[b * Dn + tid];
    __syncthreads();
    // u2: 8 threads per output dim (1024 thr / 128 dims)
    {
        const int d = tid >> 3, e8 = tid & 7;
        const float4* wrow = (const float4*)(Wo + (size_t)d * Dn + e8 * 16);
        const float4* su4 = (const float4*)(sU + e8 * 16);
        float acc = 0.f;
#pragma unroll
        for (int k = 0; k < 4; ++k) {
            const float4 w = wrow[k], u = su4[k];
            acc = fmaf(w.x, u.x, fmaf(w.y, u.y, fmaf(w.z, u.z, fmaf(w.w, u.w, acc))));
        }
        acc += __shfl_xor(acc, 1, 64);
        acc += __shfl_xor(acc, 2, 64);
        acc += __shfl_xor(acc, 4, 64);
        if (e8 == 0) sU2[d] = acc + bo[d];
    }
    __syncthreads();

    // logits: 32 groups of 32 lanes; 4-deep batched NONTEMPORAL loads
    // (K_lg is read-once 134MB: keep it out of L3 so K/V stay resident)
    const v4f* __restrict__ Kl = (const v4f*)(K_lg + (size_t)b * Nn * Dn);
    const int* __restrict__ mrow = mask + (size_t)b * Nn;
    const int grp = tid >> 5, l32 = tid & 31;
    const v4f u2f = ((const v4f*)sU2)[l32];
    const float sc = 0.08838834764831845f;   // 1/sqrt(128)
#pragma unroll
    for (int it0 = 0; it0 < 32; it0 += 4) {
        v4f kl[4];
#pragma unroll
        for (int j = 0; j < 4; ++j)
            kl[j] = __builtin_nontemporal_load(&Kl[(size_t)(grp + 32 * (it0 + j)) * 32 + l32]);
        __builtin_amdgcn_sched_barrier(0);
#pragma unroll
        for (int j = 0; j < 4; ++j) {
            float p = kl[j].x * u2f.x + kl[j].y * u2f.y + kl[j].z * u2f.z + kl[j].w * u2f.w;
#pragma unroll
            for (int o = 16; o >= 1; o >>= 1) p += __shfl_xor(p, o, 64);
            if (l32 == 0) {
                const int n = grp + 32 * (it0 + j);
                sL[n] = (mrow[n] == 0) ? NEG_INF : 10.0f * tanhf(p * sc);
            }
        }
    }
    __syncthreads();

    // block argmax (first-occurrence tie-break) — one key per thread
    float bv = sL[tid]; int bi = tid;
#pragma unroll
    for (int o = 32; o >= 1; o >>= 1) {
        const float ov = __shfl_xor(bv, o, 64);
        const int oi = __shfl_xor(bi, o, 64);
        if (ov > bv || (ov == bv && oi < bi)) { bv = ov; bi = oi; }
    }
    if (lane == 0) { sRv[wave] = bv; sRi[wave] = bi; }
    __syncthreads();
    bv = sRv[0]; bi = sRi[0];
#pragma unroll
    for (int w = 1; w < 16; ++w) {
        const float ov = sRv[w]; const int oi = sRi[w];
        if (ov > bv || (ov == bv && oi < bi)) { bv = ov; bi = oi; }
    }

    // sum of exp(l - max); prob at argmax = 1/sum
    float lsum = __expf(sL[tid] - bv);
#pragma unroll
    for (int o = 32; o >= 1; o >>= 1) lsum += __shfl_xor(lsum, o, 64);
    if (lane == 0) sRs[wave] = lsum;
    __syncthreads();
    if (tid == 0) {
        float tot = 0.f;
#pragma unroll
        for (int w = 0; w < 16; ++w) tot += sRs[w];
        out[b] = (float)bi;            // vertexes (as float32 values)
        out[Bn + b] = 1.0f / tot;      // probs
    }
}

extern "C" void kernel_launch(void* const* d_in, const int* in_sizes, int n_in,
                              void* d_out, int out_size, void* d_ws, size_t ws_size,
                              hipStream_t stream) {
    // inputs: x, h_g, first, last, context, K, V, K_lg, Wq, bq, Wo, bo, mask, t
    const float* h_g     = (const float*)d_in[1];
    const float* first   = (const float*)d_in[2];
    const float* last    = (const float*)d_in[3];
    const float* context = (const float*)d_in[4];
    const float* K       = (const float*)d_in[5];
    const float* V       = (const float*)d_in[6];
    const float* K_lg    = (const float*)d_in[7];
    const float* Wq      = (const float*)d_in[8];
    const float* bq      = (const float*)d_in[9];
    const float* Wo      = (const float*)d_in[10];
    const float* bo      = (const float*)d_in[11];
    const int*   mask    = (const int*)d_in[12];
    float* out = (float*)d_out;

    float* Qws = (float*)d_ws;             // B*D floats
    float* Uws = Qws + Bn * Dn;            // B*D floats

    k_q   <<<Bn,  128, 0, stream>>>(h_g, first, last, context, Wq, bq, Qws);
    k_attn<<<Bn, 1024, 0, stream>>>(Qws, K, V, mask, Uws);
    k_ptr <<<Bn, 1024, 0, stream>>>(Uws, Wo, bo, K_lg, mask, out);
}